// Round 1
// 91.169 us; speedup vs baseline: 1.0241x; 1.0241x over previous
//
#include <hip/hip_runtime.h>

// Problem constants (from reference): B=256, IN=1024, OUT=1024, fp32.
#define BB   256
#define IN_  1024
#define OUTN 1024

// Geometry (round-6): 16(b) x 16(o) tile, 512 threads, TWO threads per
// output cell (intra-block K-split: thread-half h covers float4 slots
// 8m+4h of every staged chunk). Same 33.3 KB LDS -> still 4 blocks/CU,
// but now 8 waves/block = 32 waves/CU (8 waves/SIMD, was 4). The kernel
// is trans-pipe bound (256M v_exp_f32, quarter rate); with 4 waves/SIMD
// issue density was ~47% (VALUBusy 60) -- doubling resident waves fills
// the stall holes around the 8-cycle exp and 120-cycle ds_read latencies.
// Per-wave LDS access pattern is h-uniform and identical to round-5
// (x: 4-row broadcast, w: 2-way alias -- both free, 0 bank conflicts).
#define TB  16
#define TO  16
#define KC  256          // i per LDS stage (4 stages)
#define NS  (IN_ / KC)
#define PAD 4            // row stride 260 floats = 1040 B (16B-aligned, 2-way banks)

#define LOG2E 1.4426950408889634f

typedef float v2f __attribute__((ext_vector_type(2)));
typedef float v4f __attribute__((ext_vector_type(4)));

// CDNA2+ packed fp32 (VOP3P): 2 fp32 lanes per instruction, same 2-cyc issue
// as scalar VALU -> halves full-rate issue. No literal operands in asm.
__device__ __forceinline__ v2f pk_mul(v2f a, v2f b) {
    v2f d; asm("v_pk_mul_f32 %0, %1, %2" : "=v"(d) : "v"(a), "v"(b)); return d;
}
__device__ __forceinline__ v2f pk_add(v2f a, v2f b) {
    v2f d; asm("v_pk_add_f32 %0, %1, %2" : "=v"(d) : "v"(a), "v"(b)); return d;
}
__device__ __forceinline__ v2f pk_fma(v2f a, v2f b, v2f c) {
    v2f d; asm("v_pk_fma_f32 %0, %1, %2, %3" : "=v"(d) : "v"(a), "v"(b), "v"(c)); return d;
}

// Barrier that drains only LDS ops (lgkmcnt), NOT vmcnt: prefetched global
// loads stay in flight across the barrier (unlike __syncthreads, which the
// compiler lowers with a full vmcnt(0) drain -- the m97-style stall).
__device__ __forceinline__ void lds_barrier() {
    asm volatile("s_waitcnt lgkmcnt(0)\n\ts_barrier" ::: "memory");
}

// leaky_clamp(v,0,1,0.1) == med3(v, 0.1*v, 0.9 + 0.1*v):
//   v<0: 0.1v is median; 0<=v<=1: v is median; v>1: 0.9+0.1v = 1+0.1(v-1).
__device__ __forceinline__ float leaky_clamp01(float v) {
    return __builtin_amdgcn_fmed3f(v, 0.1f * v, fmaf(0.1f, v, 0.9f));
}

// Numerics: |tau*z| <= ~0.9 (x~N(0,1), aw in [-0.016,0.16], tau=exp(0)=1),
// so softmax needs NO max-subtraction pass: d=sum(exp2(t)), n=sum(exp2(t)*t)
// with t = (tau*log2e*x)*aw; s = n / (d * tau * log2e). The h-split only
// repartitions the sums (pure addition) -- numerics unchanged.
__global__ __launch_bounds__(512, 8)
void esm_fused_kernel(const float* __restrict__ x,
                      const float* __restrict__ w,
                      const float* __restrict__ log_tau,
                      float* __restrict__ out) {
    __shared__ float xs[TB][KC + PAD];   // 16 x 260 floats = 16.6 KB
    __shared__ float wls[TO][KC + PAD];  // 16 x 260 floats = 16.6 KB

    const int tid = threadIdx.x;        // 0..511
    const int bid = blockIdx.x;
    // ot in low bits: one XCD's resident blocks span few o-tiles -> w
    // footprint ~512 KB (fits 4 MB per-XCD L2); x (1 MB) caches everywhere.
    const int bt = bid >> 6;            // 0..15
    const int ot = bid & 63;            // 0..63
    const int b0 = bt * TB;
    const int o0 = ot * TO;

    const float scale = __expf(log_tau[0]) * LOG2E;  // tau * log2(e)

    // Two threads per cell: cell = tid&255, half h = tid>>8. Waves are
    // h-uniform (tids 0..255 = h0, 256..511 = h1) -> per-wave LDS read
    // pattern identical to the 256-thread version (no new bank aliasing).
    const int cell = tid & 255;
    const int h    = tid >> 8;          // 0 or 1
    const int tx = cell & 15;           // o within tile
    const int ty = cell >> 4;           // b within tile
    const int ih = h << 2;              // float4-slot offset within each 8

    // Staging decode: f = tid + t*512 -> row = (tid>>6)+8t, i4 = (tid&63)*4.
    // 64-lane clusters read 1 KB contiguous (coalesced); LDS writes are
    // contiguous b128 (conflict-free).
    const int srow = tid >> 6;          // 0..7
    const int si4  = (tid & 63) << 2;   // 0..252

    // Prefetch stage 0 into registers (4 float4 = 16 VGPRs, was 32).
    float4 rx[2], rw[2];
    #pragma unroll
    for (int t = 0; t < 2; ++t) {
        const int row = srow + t * 8;
        rx[t] = *(const float4*)&x[(size_t)(b0 + row) * IN_ + si4];
        rw[t] = *(const float4*)&w[(size_t)(o0 + row) * IN_ + si4];
    }

    v2f d0 = {0.f, 0.f}, d1 = {0.f, 0.f};
    v2f n0 = {0.f, 0.f}, n1 = {0.f, 0.f};

    #pragma unroll
    for (int s = 0; s < NS; ++s) {
        if (s) lds_barrier();   // stage s-1 readers done before overwrite
        // Store prefetched registers to LDS (x pre-scaled, w pre-clamped).
        // Compiler inserts the precise vmcnt waits for rx/rw here.
        #pragma unroll
        for (int t = 0; t < 2; ++t) {
            const int row = srow + t * 8;
            const float4 xv = rx[t];
            float4 xo;
            xo.x = xv.x * scale; xo.y = xv.y * scale;
            xo.z = xv.z * scale; xo.w = xv.w * scale;
            *(float4*)&xs[row][si4] = xo;
            const float4 wv = rw[t];
            float4 wo;
            wo.x = leaky_clamp01(wv.x); wo.y = leaky_clamp01(wv.y);
            wo.z = leaky_clamp01(wv.z); wo.w = leaky_clamp01(wv.w);
            *(float4*)&wls[row][si4] = wo;
        }
        // Issue next stage's global loads BEFORE the barrier: they remain
        // in flight (vmcnt) during this stage's compute.
        if (s + 1 < NS) {
            const int i0n = (s + 1) * KC;
            #pragma unroll
            for (int t = 0; t < 2; ++t) {
                const int row = srow + t * 8;
                rx[t] = *(const float4*)&x[(size_t)(b0 + row) * IN_ + i0n + si4];
                rw[t] = *(const float4*)&w[(size_t)(o0 + row) * IN_ + i0n + si4];
            }
        }
        lds_barrier();          // LDS writes visible; prefetch stays in flight

        // Inner: this thread covers float4 slots i+4h, i.e. half of each
        // staged chunk (128 of 256 i's). Per 8-i step: 2 ds_read_b128
        // (x: 16-lane broadcast, w: 2-way bank alias -- both free) feed
        // 2 pk_mul + 4 exp + 2 pk_add + 2 pk_fma for its 4 elements.
        #pragma unroll 4
        for (int i = 0; i < KC; i += 8) {
            const v4f xa = *(const v4f*)&xs[ty][i + ih];
            const v4f wa = *(const v4f*)&wls[tx][i + ih];
            const v2f xl = __builtin_shufflevector(xa, xa, 0, 1);
            const v2f xh = __builtin_shufflevector(xa, xa, 2, 3);
            const v2f wl = __builtin_shufflevector(wa, wa, 0, 1);
            const v2f wh = __builtin_shufflevector(wa, wa, 2, 3);
            const v2f t0 = pk_mul(xl, wl);
            const v2f t1 = pk_mul(xh, wh);
            v2f e0, e1;
            e0.x = __builtin_amdgcn_exp2f(t0.x);
            e0.y = __builtin_amdgcn_exp2f(t0.y);
            e1.x = __builtin_amdgcn_exp2f(t1.x);
            e1.y = __builtin_amdgcn_exp2f(t1.y);
            d0 = pk_add(d0, e0);
            d1 = pk_add(d1, e1);
            n0 = pk_fma(e0, t0, n0);
            n1 = pk_fma(e1, t1, n1);
        }
    }

    float dsum = (d0.x + d0.y) + (d1.x + d1.y);
    float nsum = (n0.x + n0.y) + (n1.x + n1.y);

    // Combine the two K-halves through reused LDS (xs is dead now).
    // 2 KB scratch, stride-2 dword writes (2-way, free) -- negligible.
    __syncthreads();            // all inner-loop LDS reads complete
    float* sc = &xs[0][0];
    if (h) {
        sc[cell * 2]     = dsum;
        sc[cell * 2 + 1] = nsum;
    }
    __syncthreads();
    if (!h) {
        dsum += sc[cell * 2];
        nsum += sc[cell * 2 + 1];
        // Epilogue: s = n / (d * scale). 64 lanes -> 4 rows x 16 consecutive
        // floats (64B segments); 1 MB total, negligible.
        out[(size_t)(b0 + ty) * OUTN + o0 + tx] = nsum / (dsum * scale);
    }
}

extern "C" void kernel_launch(void* const* d_in, const int* in_sizes, int n_in,
                              void* d_out, int out_size, void* d_ws, size_t ws_size,
                              hipStream_t stream) {
    const float* x  = (const float*)d_in[0];   // (256, 1024)
    const float* w  = (const float*)d_in[1];   // (1024, 1024)
    const float* lt = (const float*)d_in[2];   // scalar log_tau
    float* out = (float*)d_out;                // (256, 1024)

    esm_fused_kernel<<<(BB / TB) * (OUTN / TO), 512, 0, stream>>>(x, w, lt, out);
}